// Round 7
// baseline (430.740 us; speedup 1.0000x reference)
//
#include <hip/hip_runtime.h>

#define NXc 468
#define NYc 468
#define CANVASc (468 * 468)   // 219024
#define NPTS 400000
#define RUN 16
#define NRUNS (NPTS / RUN)    // 25000 exactly

#define PCMIN_X (-74.88f)
#define PCMIN_Y (-74.88f)
#define VOX_X 0.32f
#define VOX_Y 0.32f
#define OFF_X (-74.72f)
#define OFF_Y (-74.72f)
#define OFF_Z (1.0f)

__device__ __forceinline__ float rlf(float x, int p) {
    return __int_as_float(__builtin_amdgcn_readlane(__float_as_int(x), p));
}
__device__ __forceinline__ int rli(int x, int p) {
    return __builtin_amdgcn_readlane(x, p);
}

__device__ __forceinline__ int voxel_cell(float x, float y, int& cx, int& cy) {
    cx = (int)floorf((x - PCMIN_X) / VOX_X);
    cy = (int)floorf((y - PCMIN_Y) / VOX_Y);
    cx = min(max(cx, 0), NXc - 1);
    cy = min(max(cy, 0), NYc - 1);
    return cy * NXc + cx;
}

// Pass 0: per-voxel count + xyz sums
__global__ __launch_bounds__(256) void k_stats(const float* __restrict__ pts,
                                               int* __restrict__ cnt,
                                               float4* __restrict__ vsum4) {
    int i = blockIdx.x * 256 + threadIdx.x;
    if (i >= NPTS) return;
    float x = pts[i * 5 + 0], y = pts[i * 5 + 1], z = pts[i * 5 + 2];
    int cx, cy;
    int fl = voxel_cell(x, y, cx, cy);
    atomicAdd(&cnt[fl], 1);
    float* s = (float*)&vsum4[fl];
    unsafeAtomicAdd(s + 0, x);
    unsafeAtomicAdd(s + 1, y);
    unsafeAtomicAdd(s + 2, z);
}

// Pass 1: exclusive-scan alloc -> cursor; vsum -> vmean (in place)
__global__ __launch_bounds__(256) void k_alloc(const int* __restrict__ cnt,
                                               float4* __restrict__ vsum4,
                                               int* __restrict__ cursor,
                                               int* __restrict__ gcur) {
    int v = blockIdx.x * 256 + threadIdx.x;
    int lane = threadIdx.x & 63;
    int c = (v < CANVASc) ? cnt[v] : 0;
    int scan = c;
    #pragma unroll
    for (int off = 1; off < 64; off <<= 1) {
        int t = __shfl_up(scan, off, 64);
        if (lane >= off) scan += t;
    }
    int total = __shfl(scan, 63, 64);
    int base = 0;
    if (lane == 0 && total > 0) base = atomicAdd(gcur, total);
    base = __shfl(base, 0, 64);
    if (v < CANVASc) {
        cursor[v] = base + scan - c;
        float inv = (c > 0) ? 1.0f / (float)c : 0.f;
        float4 s = vsum4[v];
        vsum4[v] = make_float4(s.x * inv, s.y * inv, s.z * inv, 0.f);
    }
}

// Pass 2: scatter slim point records into voxel-contiguous sorted order (20 B/pt)
__global__ __launch_bounds__(256) void k_scatter(const float* __restrict__ pts,
                                                 int* __restrict__ cursor,
                                                 float4* __restrict__ sp4a,
                                                 float* __restrict__ sp1) {
    int i = blockIdx.x * 256 + threadIdx.x;
    if (i >= NPTS) return;
    float x = pts[i * 5 + 0], y = pts[i * 5 + 1], z = pts[i * 5 + 2];
    float e0 = pts[i * 5 + 3], e1 = pts[i * 5 + 4];
    int cx, cy;
    int fl = voxel_cell(x, y, cx, cy);
    int pos = atomicAdd(&cursor[fl], 1);
    sp4a[pos] = make_float4(x, y, z, e0);
    sp1[pos] = e1;
}

// Per-lane (j<RUN) feature prep: recompute voxel id, f_center, gather vmean.
// Returns all per-point values in registers for readlane broadcast.
struct PtRegs {
    float4 A;              // x,y,z,e0
    float  e1, fcx, fcy, fcz;
    float  mx, my, mz;
    int    vx;
};
__device__ __forceinline__ PtRegs load_pt(const float4* __restrict__ sp4a,
                                          const float* __restrict__ sp1,
                                          const float4* __restrict__ vmean4,
                                          int base, int j) {
    PtRegs r;
    r.A = make_float4(0.f, 0.f, 0.f, 0.f);
    r.e1 = r.fcx = r.fcy = r.fcz = r.mx = r.my = r.mz = 0.f;
    r.vx = 0;
    if (j < RUN) {
        r.A = sp4a[base + j];
        r.e1 = sp1[base + j];
        int cx, cy;
        r.vx = voxel_cell(r.A.x, r.A.y, cx, cy);
        r.fcx = r.A.x - (cx * VOX_X + OFF_X);
        r.fcy = r.A.y - (cy * VOX_Y + OFF_Y);
        r.fcz = r.A.z - OFF_Z;
        float4 m = vmean4[r.vx];
        r.mx = m.x; r.my = m.y; r.mz = m.z;
    }
    return r;
}

// kA: v1 = segment_max(relu(feat @ W1)). Wave = 16 sorted points, lane = col j.
// Interior segments: plain store. Run-edge segments: atomicMax (poison 0xAA is
// negative int, relu values >= 0, so no memset needed).
__global__ __launch_bounds__(256) void kA(const float4* __restrict__ sp4a,
                                          const float* __restrict__ sp1,
                                          const float4* __restrict__ vmean4,
                                          const float* __restrict__ W1,
                                          float* __restrict__ v1) {
    int wave = blockIdx.x * 4 + (threadIdx.x >> 6);
    int j = threadIdx.x & 63;
    int base = wave * RUN;

    PtRegs P = load_pt(sp4a, sp1, vmean4, base, j);

    float w[11];
    #pragma unroll
    for (int ii = 0; ii < 11; ii++) w[ii] = W1[ii * 64 + j];
    const float wx = w[0] + w[5], wy = w[1] + w[6], wz = w[2] + w[7];

    const int first = rli(P.vx, 0), last = rli(P.vx, RUN - 1);
    int vprev = first;
    float rmax = 0.f;
    for (int p = 0; p < RUN; p++) {
        int vp = rli(P.vx, p);
        if (vp != vprev) {
            size_t o = (size_t)vprev * 64 + j;
            if (vprev == first || vprev == last) atomicMax((int*)v1 + o, __float_as_int(rmax));
            else v1[o] = rmax;
            vprev = vp; rmax = 0.f;
        }
        float x = rlf(P.A.x, p), y = rlf(P.A.y, p), z = rlf(P.A.z, p), e0 = rlf(P.A.w, p);
        float e1 = rlf(P.e1, p), fcx = rlf(P.fcx, p), fcy = rlf(P.fcy, p), fcz = rlf(P.fcz, p);
        float mx = rlf(P.mx, p), my = rlf(P.my, p), mz = rlf(P.mz, p);
        float pf = x * wx + y * wy + z * wz + e0 * w[3] + e1 * w[4]
                 + fcx * w[8] + fcy * w[9] + fcz * w[10]
                 - (mx * w[5] + my * w[6] + mz * w[7]);
        rmax = fmaxf(rmax, pf);   // pf<0 -> relu 0 == rmax init, ok
    }
    {
        size_t o = (size_t)vprev * 64 + j;
        atomicMax((int*)v1 + o, __float_as_int(rmax));   // last segment always edge
    }
}

// kB: out = segment_max(relu(pf1 @ W2lo + v1 @ W2hi)). Wave = 16 sorted points.
// pf1 recomputed, staged in LDS; W2 both halves register/AGPR-pinned; v1 rows
// for all 16 points prefetched coalesced upfront; accv computed at each
// segment flush via readlane dot (this absorbed the former kC kernel).
__global__ __launch_bounds__(256) void kB(const float4* __restrict__ sp4a,
                                          const float* __restrict__ sp1,
                                          const float4* __restrict__ vmean4,
                                          const float* __restrict__ W1,
                                          const float* __restrict__ W2,
                                          const float* __restrict__ v1,
                                          float* __restrict__ out) {
    __shared__ float s_pf1[4][RUN][64];   // 16 KB
    int wslot = threadIdx.x >> 6;
    int wave = blockIdx.x * 4 + wslot;
    int j = threadIdx.x & 63;
    int base = wave * RUN;

    PtRegs P = load_pt(sp4a, sp1, vmean4, base, j);

    // prefetch v1 row for each point's voxel (coalesced 256B loads, overlapped)
    float vrow[RUN];
    #pragma unroll
    for (int p = 0; p < RUN; p++) {
        int vp = rli(P.vx, p);
        vrow[p] = v1[(size_t)vp * 64 + j];
    }

    float w[11];
    #pragma unroll
    for (int ii = 0; ii < 11; ii++) w[ii] = W1[ii * 64 + j];
    const float wx = w[0] + w[5], wy = w[1] + w[6], wz = w[2] + w[7];

    float w2a[64], w2b[64];
    #pragma unroll
    for (int k = 0; k < 64; k++) w2a[k] = W2[k * 64 + j];
    #pragma unroll
    for (int k = 0; k < 64; k++) w2b[k] = W2[(64 + k) * 64 + j];

    // phase 1: pf1 rows -> LDS
    for (int p = 0; p < RUN; p++) {
        float x = rlf(P.A.x, p), y = rlf(P.A.y, p), z = rlf(P.A.z, p), e0 = rlf(P.A.w, p);
        float e1 = rlf(P.e1, p), fcx = rlf(P.fcx, p), fcy = rlf(P.fcy, p), fcz = rlf(P.fcz, p);
        float mx = rlf(P.mx, p), my = rlf(P.my, p), mz = rlf(P.mz, p);
        float pf = x * wx + y * wy + z * wz + e0 * w[3] + e1 * w[4]
                 + fcx * w[8] + fcy * w[9] + fcz * w[10]
                 - (mx * w[5] + my * w[6] + mz * w[7]);
        s_pf1[wslot][p][j] = fmaxf(pf, 0.f);
    }
    __builtin_amdgcn_wave_barrier();

    const int first = rli(P.vx, 0), last = rli(P.vx, RUN - 1);
    int vprev = first;
    float row_cur = vrow[0];            // v1 row of current segment's voxel
    float smax = -3.4e38f;
    #pragma unroll
    for (int p = 0; p < RUN; p++) {
        int vp = rli(P.vx, p);
        if (vp != vprev) {
            // flush segment vprev: accv = v1row . W2hi col j, then relu(max+accv)
            float b0 = 0.f, b1 = 0.f;
            #pragma unroll
            for (int k = 0; k < 64; k += 2) {
                b0 += rlf(row_cur, k) * w2b[k];
                b1 += rlf(row_cur, k + 1) * w2b[k + 1];
            }
            float r = fmaxf((b0 + b1) + smax, 0.f);
            size_t o = (size_t)vprev * 64 + j;
            if (vprev == first || vprev == last) atomicMax((int*)out + o, __float_as_int(r));
            else out[o] = r;
            vprev = vp; smax = -3.4e38f;
            row_cur = vrow[p];          // p is compile-time (full unroll)
        }
        const float4* pr = (const float4*)s_pf1[wslot][p];
        float a0 = 0.f, a1 = 0.f, a2 = 0.f, a3 = 0.f;
        #pragma unroll
        for (int q = 0; q < 16; q += 4) {
            float4 u0 = pr[q + 0], u1 = pr[q + 1], u2 = pr[q + 2], u3 = pr[q + 3];
            a0 += u0.x * w2a[4 * q + 0]  + u0.y * w2a[4 * q + 1]
                + u0.z * w2a[4 * q + 2]  + u0.w * w2a[4 * q + 3];
            a1 += u1.x * w2a[4 * q + 4]  + u1.y * w2a[4 * q + 5]
                + u1.z * w2a[4 * q + 6]  + u1.w * w2a[4 * q + 7];
            a2 += u2.x * w2a[4 * q + 8]  + u2.y * w2a[4 * q + 9]
                + u2.z * w2a[4 * q + 10] + u2.w * w2a[4 * q + 11];
            a3 += u3.x * w2a[4 * q + 12] + u3.y * w2a[4 * q + 13]
                + u3.z * w2a[4 * q + 14] + u3.w * w2a[4 * q + 15];
        }
        smax = fmaxf(smax, (a0 + a1) + (a2 + a3));
    }
    {
        float b0 = 0.f, b1 = 0.f;
        #pragma unroll
        for (int k = 0; k < 64; k += 2) {
            b0 += rlf(row_cur, k) * w2b[k];
            b1 += rlf(row_cur, k + 1) * w2b[k + 1];
        }
        float r = fmaxf((b0 + b1) + smax, 0.f);
        size_t o = (size_t)vprev * 64 + j;
        atomicMax((int*)out + o, __float_as_int(r));   // last segment always edge
    }
}

extern "C" void kernel_launch(void* const* d_in, const int* in_sizes, int n_in,
                              void* d_out, int out_size, void* d_ws, size_t ws_size,
                              hipStream_t stream) {
    const float* pts = (const float*)d_in[0];
    const float* W1  = (const float*)d_in[1];
    const float* W2  = (const float*)d_in[2];
    float* out = (float*)d_out;

    // ws layout (~69 MB):
    float4* sp4a  = (float4*)d_ws;                   // NPTS float4
    float4* vsum4 = sp4a + NPTS;                     // CANVAS (becomes vmean4)
    int*    cnt   = (int*)(vsum4 + CANVASc);         // CANVAS
    int*    gcur  = cnt + CANVASc;                   // 1
    int*    cursor= gcur + 1;                        // CANVAS
    float*  sp1   = (float*)(cursor + CANVASc);      // NPTS
    float*  v1    = sp1 + NPTS;                      // CANVAS*64

    // zero vsum4 + cnt + gcur in one shot (contiguous); zero out (empty rows)
    hipMemsetAsync(vsum4, 0, (size_t)CANVASc * 16 + (size_t)CANVASc * 4 + 4, stream);
    hipMemsetAsync(d_out, 0, (size_t)out_size * sizeof(float), stream);

    int gpts = (NPTS + 255) / 256;
    int gvox = (CANVASc + 255) / 256;
    k_stats  <<<gpts, 256, 0, stream>>>(pts, cnt, vsum4);
    k_alloc  <<<gvox, 256, 0, stream>>>(cnt, vsum4, cursor, gcur);
    k_scatter<<<gpts, 256, 0, stream>>>(pts, cursor, sp4a, sp1);
    kA<<<NRUNS / 4, 256, 0, stream>>>(sp4a, sp1, vsum4, W1, v1);
    kB<<<NRUNS / 4, 256, 0, stream>>>(sp4a, sp1, vsum4, W1, W2, v1, out);
}

// Round 8
// 304.365 us; speedup vs baseline: 1.4152x; 1.4152x over previous
//
#include <hip/hip_runtime.h>

#define NXc 468
#define NYc 468
#define CANVASc (468 * 468)   // 219024
#define NPTS 400000
#define RUN 16
#define NRUNS (NPTS / RUN)    // 25000 exactly

#define PCMIN_X (-74.88f)
#define PCMIN_Y (-74.88f)
#define VOX_X 0.32f
#define VOX_Y 0.32f
#define OFF_X (-74.72f)
#define OFF_Y (-74.72f)
#define OFF_Z (1.0f)

typedef __attribute__((ext_vector_type(8))) short v8s;   // 8 bf16 (4 VGPRs)
typedef __attribute__((ext_vector_type(4))) float v4f;   // MFMA acc

__device__ __forceinline__ float rlf(float x, int p) {
    return __int_as_float(__builtin_amdgcn_readlane(__float_as_int(x), p));
}
__device__ __forceinline__ int rli(int x, int p) {
    return __builtin_amdgcn_readlane(x, p);
}
// bf16 RNE bits (top-aligned fp32 pattern)
__device__ __forceinline__ unsigned bfh(float x) {
    unsigned u = __float_as_uint(x);
    unsigned r = u + 0x7FFFu + ((u >> 16) & 1u);
    return r & 0xFFFF0000u;
}
// split 8 fp32 -> bf16 hi + lo fragments
__device__ __forceinline__ void split8(const float* f, v8s& h, v8s& l) {
    #pragma unroll
    for (int i = 0; i < 8; i++) {
        unsigned hb = bfh(f[i]);
        h[i] = (short)(hb >> 16);
        float lo = f[i] - __uint_as_float(hb);
        l[i] = (short)(bfh(lo) >> 16);
    }
}

__device__ __forceinline__ int voxel_cell(float x, float y, int& cx, int& cy) {
    cx = (int)floorf((x - PCMIN_X) / VOX_X);
    cy = (int)floorf((y - PCMIN_Y) / VOX_Y);
    cx = min(max(cx, 0), NXc - 1);
    cy = min(max(cy, 0), NYc - 1);
    return cy * NXc + cx;
}

// Pass 0: per-voxel count + xyz sums
__global__ __launch_bounds__(256) void k_stats(const float* __restrict__ pts,
                                               int* __restrict__ cnt,
                                               float4* __restrict__ vsum4) {
    int i = blockIdx.x * 256 + threadIdx.x;
    if (i >= NPTS) return;
    float x = pts[i * 5 + 0], y = pts[i * 5 + 1], z = pts[i * 5 + 2];
    int cx, cy;
    int fl = voxel_cell(x, y, cx, cy);
    atomicAdd(&cnt[fl], 1);
    float* s = (float*)&vsum4[fl];
    unsafeAtomicAdd(s + 0, x);
    unsafeAtomicAdd(s + 1, y);
    unsafeAtomicAdd(s + 2, z);
}

// Pass 1: exclusive-scan alloc -> cursor; vsum -> vmean (in place)
__global__ __launch_bounds__(256) void k_alloc(const int* __restrict__ cnt,
                                               float4* __restrict__ vsum4,
                                               int* __restrict__ cursor,
                                               int* __restrict__ gcur) {
    int v = blockIdx.x * 256 + threadIdx.x;
    int lane = threadIdx.x & 63;
    int c = (v < CANVASc) ? cnt[v] : 0;
    int scan = c;
    #pragma unroll
    for (int off = 1; off < 64; off <<= 1) {
        int t = __shfl_up(scan, off, 64);
        if (lane >= off) scan += t;
    }
    int total = __shfl(scan, 63, 64);
    int base = 0;
    if (lane == 0 && total > 0) base = atomicAdd(gcur, total);
    base = __shfl(base, 0, 64);
    if (v < CANVASc) {
        cursor[v] = base + scan - c;
        float inv = (c > 0) ? 1.0f / (float)c : 0.f;
        float4 s = vsum4[v];
        vsum4[v] = make_float4(s.x * inv, s.y * inv, s.z * inv, 0.f);
    }
}

// Pass 2: scatter slim point records into voxel-contiguous sorted order
__global__ __launch_bounds__(256) void k_scatter(const float* __restrict__ pts,
                                                 int* __restrict__ cursor,
                                                 float4* __restrict__ sp4a,
                                                 float* __restrict__ sp1) {
    int i = blockIdx.x * 256 + threadIdx.x;
    if (i >= NPTS) return;
    float x = pts[i * 5 + 0], y = pts[i * 5 + 1], z = pts[i * 5 + 2];
    float e0 = pts[i * 5 + 3], e1 = pts[i * 5 + 4];
    int cx, cy;
    int fl = voxel_cell(x, y, cx, cy);
    int pos = atomicAdd(&cursor[fl], 1);
    sp4a[pos] = make_float4(x, y, z, e0);
    sp1[pos] = e1;
}

// kW: pre-convert W2 (128x64) into lane-ordered bf16 hi/lo B-fragments.
// Frag pair f = t*4+c (t=col-tile 0..3, c=K-chunk 0..3 covering W2 rows c*32..).
// B[k][n]: n = lane&15, k = c*32 + (lane>>4)*8 + i   (i = element 0..7).
__global__ __launch_bounds__(256) void kW(const float* __restrict__ W2,
                                          v8s* __restrict__ wfrag) {
    int tid = blockIdx.x * 256 + threadIdx.x;   // 1024 total
    if (tid >= 1024) return;
    int f = tid >> 6, lane = tid & 63;
    int t = f >> 2, c = f & 3;
    int q = lane >> 4, n = lane & 15;
    float v[8];
    #pragma unroll
    for (int i = 0; i < 8; i++) v[i] = W2[(c * 32 + q * 8 + i) * 64 + t * 16 + n];
    v8s h, l;
    split8(v, h, l);
    wfrag[(f * 2 + 0) * 64 + lane] = h;
    wfrag[(f * 2 + 1) * 64 + lane] = l;
}

// Per-lane (j<RUN) feature prep (round-6 known-good)
struct PtRegs {
    float4 A;
    float  e1, fcx, fcy, fcz;
    float  mx, my, mz;
    int    vx;
};
__device__ __forceinline__ PtRegs load_pt(const float4* __restrict__ sp4a,
                                          const float* __restrict__ sp1,
                                          const float4* __restrict__ vmean4,
                                          int base, int j) {
    PtRegs r;
    r.A = make_float4(0.f, 0.f, 0.f, 0.f);
    r.e1 = r.fcx = r.fcy = r.fcz = r.mx = r.my = r.mz = 0.f;
    r.vx = 0;
    if (j < RUN) {
        r.A = sp4a[base + j];
        r.e1 = sp1[base + j];
        int cx, cy;
        r.vx = voxel_cell(r.A.x, r.A.y, cx, cy);
        r.fcx = r.A.x - (cx * VOX_X + OFF_X);
        r.fcy = r.A.y - (cy * VOX_Y + OFF_Y);
        r.fcz = r.A.z - OFF_Z;
        float4 m = vmean4[r.vx];
        r.mx = m.x; r.my = m.y; r.mz = m.z;
    }
    return r;
}

// kA: v1 = segment_max(relu(feat @ W1)) — round-6 known-good.
__global__ __launch_bounds__(256) void kA(const float4* __restrict__ sp4a,
                                          const float* __restrict__ sp1,
                                          const float4* __restrict__ vmean4,
                                          const float* __restrict__ W1,
                                          float* __restrict__ v1) {
    int wave = blockIdx.x * 4 + (threadIdx.x >> 6);
    int j = threadIdx.x & 63;
    int base = wave * RUN;

    PtRegs P = load_pt(sp4a, sp1, vmean4, base, j);

    float w[11];
    #pragma unroll
    for (int ii = 0; ii < 11; ii++) w[ii] = W1[ii * 64 + j];
    const float wx = w[0] + w[5], wy = w[1] + w[6], wz = w[2] + w[7];

    const int first = rli(P.vx, 0), last = rli(P.vx, RUN - 1);
    int vprev = first;
    float rmax = 0.f;
    for (int p = 0; p < RUN; p++) {
        int vp = rli(P.vx, p);
        if (vp != vprev) {
            size_t o = (size_t)vprev * 64 + j;
            if (vprev == first || vprev == last) atomicMax((int*)v1 + o, __float_as_int(rmax));
            else v1[o] = rmax;
            vprev = vp; rmax = 0.f;
        }
        float x = rlf(P.A.x, p), y = rlf(P.A.y, p), z = rlf(P.A.z, p), e0 = rlf(P.A.w, p);
        float e1 = rlf(P.e1, p), fcx = rlf(P.fcx, p), fcy = rlf(P.fcy, p), fcz = rlf(P.fcz, p);
        float mx = rlf(P.mx, p), my = rlf(P.my, p), mz = rlf(P.mz, p);
        float pf = x * wx + y * wy + z * wz + e0 * w[3] + e1 * w[4]
                 + fcx * w[8] + fcy * w[9] + fcz * w[10]
                 - (mx * w[5] + my * w[6] + mz * w[7]);
        rmax = fmaxf(rmax, pf);
    }
    {
        size_t o = (size_t)vprev * 64 + j;
        atomicMax((int*)v1 + o, __float_as_int(rmax));
    }
}

// kB: D[p][j] = feat2[p] @ W2 col j via MFMA 16x16x32 bf16 (hi/lo 3-product),
// feat2 row p = [pf1[p] (K 0..63), v1[vox(p)] (K 64..127)] -> segment max.
// A[m][k]: m=lane&15, k=(lane>>4)*8+i (+32c). D: col=lane&15, row=(lane>>4)*4+r.
#define PSTR 68   // LDS row stride (floats): kills all bank conflicts
__global__ __launch_bounds__(256) void kB(const float4* __restrict__ sp4a,
                                          const float* __restrict__ sp1,
                                          const float4* __restrict__ vmean4,
                                          const float* __restrict__ W1,
                                          const v8s* __restrict__ wfrag,
                                          const float* __restrict__ v1,
                                          float* __restrict__ out) {
    __shared__ float s_pf[4][RUN][PSTR];   // 17408 B; pf1 staging, then D staging
    int wslot = threadIdx.x >> 6;
    int wave = blockIdx.x * 4 + wslot;
    int j = threadIdx.x & 63;
    int base = wave * RUN;

    PtRegs P = load_pt(sp4a, sp1, vmean4, base, j);

    float w[11];
    #pragma unroll
    for (int ii = 0; ii < 11; ii++) w[ii] = W1[ii * 64 + j];
    const float wx = w[0] + w[5], wy = w[1] + w[6], wz = w[2] + w[7];

    // phase 1: pf1[p][j] -> LDS (relu'd)
    for (int p = 0; p < RUN; p++) {
        float x = rlf(P.A.x, p), y = rlf(P.A.y, p), z = rlf(P.A.z, p), e0 = rlf(P.A.w, p);
        float e1 = rlf(P.e1, p), fcx = rlf(P.fcx, p), fcy = rlf(P.fcy, p), fcz = rlf(P.fcz, p);
        float mx = rlf(P.mx, p), my = rlf(P.my, p), mz = rlf(P.mz, p);
        float pf = x * wx + y * wy + z * wz + e0 * w[3] + e1 * w[4]
                 + fcx * w[8] + fcy * w[9] + fcz * w[10]
                 - (mx * w[5] + my * w[6] + mz * w[7]);
        s_pf[wslot][p][j] = fmaxf(pf, 0.f);
    }
    __builtin_amdgcn_wave_barrier();

    const int m = j & 15, q = j >> 4;

    // A-frags: chunks 0,1 from pf1 (lane-distinct LDS reads, conflict-free @ stride 68)
    v8s ah[4], al[4];
    #pragma unroll
    for (int c = 0; c < 2; c++) {
        float4 u0 = *(const float4*)&s_pf[wslot][m][c * 32 + q * 8];
        float4 u1 = *(const float4*)&s_pf[wslot][m][c * 32 + q * 8 + 4];
        float f[8] = {u0.x, u0.y, u0.z, u0.w, u1.x, u1.y, u1.z, u1.w};
        split8(f, ah[c], al[c]);
    }
    // chunks 2,3 from v1[vox(point m)] (per-point v1 row: constant within segment,
    // so max(S+T') = max(S)+T' -- the accv term rides inside the same accumulator)
    int vx_m = __builtin_amdgcn_ds_bpermute(m << 2, P.vx);
    {
        const float* vr = v1 + (size_t)vx_m * 64 + q * 8;
        #pragma unroll
        for (int c = 2; c < 4; c++) {
            float4 g0 = *(const float4*)(vr + (c - 2) * 32);
            float4 g1 = *(const float4*)(vr + (c - 2) * 32 + 4);
            float f[8] = {g0.x, g0.y, g0.z, g0.w, g1.x, g1.y, g1.z, g1.w};
            split8(f, ah[c], al[c]);
        }
    }
    __builtin_amdgcn_wave_barrier();   // all A reads done before D overwrites s_pf

    // 4 col-tiles x 4 K-chunks x 3 products (hh, lh, hl)
    #pragma unroll
    for (int t = 0; t < 4; t++) {
        v8s bh[4], bl[4];
        #pragma unroll
        for (int c = 0; c < 4; c++) {
            bh[c] = wfrag[((t * 4 + c) * 2 + 0) * 64 + j];
            bl[c] = wfrag[((t * 4 + c) * 2 + 1) * 64 + j];
        }
        v4f acc = {0.f, 0.f, 0.f, 0.f};
        #pragma unroll
        for (int c = 0; c < 4; c++) {
            acc = __builtin_amdgcn_mfma_f32_16x16x32_bf16(ah[c], bh[c], acc, 0, 0, 0);
            acc = __builtin_amdgcn_mfma_f32_16x16x32_bf16(al[c], bh[c], acc, 0, 0, 0);
            acc = __builtin_amdgcn_mfma_f32_16x16x32_bf16(ah[c], bl[c], acc, 0, 0, 0);
        }
        #pragma unroll
        for (int r = 0; r < 4; r++) s_pf[wslot][q * 4 + r][t * 16 + m] = acc[r];
    }
    __builtin_amdgcn_wave_barrier();

    // epilogue: round-6 segment flush (1 ds_read_b32 per point per lane)
    const int first = rli(P.vx, 0), last = rli(P.vx, RUN - 1);
    int vprev = first;
    float smax = -3.4e38f;
    for (int p = 0; p < RUN; p++) {
        int vp = rli(P.vx, p);
        if (vp != vprev) {
            float r = fmaxf(smax, 0.f);
            size_t o = (size_t)vprev * 64 + j;
            if (vprev == first || vprev == last) atomicMax((int*)out + o, __float_as_int(r));
            else out[o] = r;
            vprev = vp; smax = -3.4e38f;
        }
        smax = fmaxf(smax, s_pf[wslot][p][j]);
    }
    {
        float r = fmaxf(smax, 0.f);
        size_t o = (size_t)vprev * 64 + j;
        atomicMax((int*)out + o, __float_as_int(r));
    }
}

extern "C" void kernel_launch(void* const* d_in, const int* in_sizes, int n_in,
                              void* d_out, int out_size, void* d_ws, size_t ws_size,
                              hipStream_t stream) {
    const float* pts = (const float*)d_in[0];
    const float* W1  = (const float*)d_in[1];
    const float* W2  = (const float*)d_in[2];
    float* out = (float*)d_out;

    // ws layout (16B-aligned where vector-loaded):
    float4* sp4a  = (float4*)d_ws;                   // NPTS
    float4* vsum4 = sp4a + NPTS;                     // CANVAS
    int*    cnt   = (int*)(vsum4 + CANVASc);         // CANVAS
    int*    cursor= cnt + CANVASc;                   // CANVAS
    float*  sp1   = (float*)(cursor + CANVASc);      // NPTS
    float*  v1    = sp1 + NPTS;                      // CANVAS*64 (16B-aligned)
    v8s*    wfrag = (v8s*)(v1 + (size_t)CANVASc * 64); // 2048 v8s = 32 KB
    int*    gcur  = (int*)(wfrag + 2048);            // 1

    hipMemsetAsync(vsum4, 0, (size_t)CANVASc * 16 + (size_t)CANVASc * 4, stream); // vsum4+cnt
    hipMemsetAsync(gcur, 0, sizeof(int), stream);
    hipMemsetAsync(d_out, 0, (size_t)out_size * sizeof(float), stream);           // empty rows

    int gpts = (NPTS + 255) / 256;
    int gvox = (CANVASc + 255) / 256;
    k_stats  <<<gpts, 256, 0, stream>>>(pts, cnt, vsum4);
    k_alloc  <<<gvox, 256, 0, stream>>>(cnt, vsum4, cursor, gcur);
    k_scatter<<<gpts, 256, 0, stream>>>(pts, cursor, sp4a, sp1);
    kW<<<4, 256, 0, stream>>>(W2, wfrag);
    kA<<<NRUNS / 4, 256, 0, stream>>>(sp4a, sp1, vsum4, W1, v1);
    kB<<<NRUNS / 4, 256, 0, stream>>>(sp4a, sp1, vsum4, W1, wfrag, v1, out);
}

// Round 9
// 272.468 us; speedup vs baseline: 1.5809x; 1.1171x over previous
//
#include <hip/hip_runtime.h>

#define NXc 468
#define NYc 468
#define CANVASc (468 * 468)   // 219024
#define NPTS 400000
#define RUN 16
#define NRUNS (NPTS / RUN)    // 25000 exactly

#define PCMIN_X (-74.88f)
#define PCMIN_Y (-74.88f)
#define VOX_X 0.32f
#define VOX_Y 0.32f
#define OFF_X (-74.72f)
#define OFF_Y (-74.72f)
#define OFF_Z (1.0f)

typedef __attribute__((ext_vector_type(8))) short v8s;   // 8 bf16 (4 VGPRs)
typedef __attribute__((ext_vector_type(4))) float v4f;   // MFMA acc

__device__ __forceinline__ float rlf(float x, int p) {
    return __int_as_float(__builtin_amdgcn_readlane(__float_as_int(x), p));
}
__device__ __forceinline__ int rli(int x, int p) {
    return __builtin_amdgcn_readlane(x, p);
}
// bf16 RNE bits (top-aligned fp32 pattern)
__device__ __forceinline__ unsigned bfh(float x) {
    unsigned u = __float_as_uint(x);
    unsigned r = u + 0x7FFFu + ((u >> 16) & 1u);
    return r & 0xFFFF0000u;
}
__device__ __forceinline__ void split8(const float* f, v8s& h, v8s& l) {
    #pragma unroll
    for (int i = 0; i < 8; i++) {
        unsigned hb = bfh(f[i]);
        h[i] = (short)(hb >> 16);
        float lo = f[i] - __uint_as_float(hb);
        l[i] = (short)(bfh(lo) >> 16);
    }
}

__device__ __forceinline__ int voxel_cell(float x, float y, int& cx, int& cy) {
    cx = (int)floorf((x - PCMIN_X) / VOX_X);
    cy = (int)floorf((y - PCMIN_Y) / VOX_Y);
    cx = min(max(cx, 0), NXc - 1);
    cy = min(max(cy, 0), NYc - 1);
    return cy * NXc + cx;
}

// Pass 0: per-voxel counts ONLY (sums moved post-sort to kA0)
__global__ __launch_bounds__(256) void k_stats(const float* __restrict__ pts,
                                               int* __restrict__ cnt) {
    int i = blockIdx.x * 256 + threadIdx.x;
    if (i >= NPTS) return;
    float x = pts[i * 5 + 0], y = pts[i * 5 + 1];
    int cx, cy;
    atomicAdd(&cnt[voxel_cell(x, y, cx, cy)], 1);
}

// Pass 1: exclusive-scan alloc -> cursor
__global__ __launch_bounds__(256) void k_alloc(const int* __restrict__ cnt,
                                               int* __restrict__ cursor,
                                               int* __restrict__ gcur) {
    int v = blockIdx.x * 256 + threadIdx.x;
    int lane = threadIdx.x & 63;
    int c = (v < CANVASc) ? cnt[v] : 0;
    int scan = c;
    #pragma unroll
    for (int off = 1; off < 64; off <<= 1) {
        int t = __shfl_up(scan, off, 64);
        if (lane >= off) scan += t;
    }
    int total = __shfl(scan, 63, 64);
    int base = 0;
    if (lane == 0 && total > 0) base = atomicAdd(gcur, total);
    base = __shfl(base, 0, 64);
    if (v < CANVASc) cursor[v] = base + scan - c;
}

// Pass 2: scatter slim point records into voxel-contiguous sorted order
__global__ __launch_bounds__(256) void k_scatter(const float* __restrict__ pts,
                                                 int* __restrict__ cursor,
                                                 float4* __restrict__ sp4a,
                                                 float* __restrict__ sp1) {
    int i = blockIdx.x * 256 + threadIdx.x;
    if (i >= NPTS) return;
    float x = pts[i * 5 + 0], y = pts[i * 5 + 1], z = pts[i * 5 + 2];
    float e0 = pts[i * 5 + 3], e1 = pts[i * 5 + 4];
    int cx, cy;
    int fl = voxel_cell(x, y, cx, cy);
    int pos = atomicAdd(&cursor[fl], 1);
    sp4a[pos] = make_float4(x, y, z, e0);
    sp1[pos] = e1;
}

// kA0: per-voxel xyz sums from SORTED data. Wave = 16 points. Segment sums are
// wave-uniform via readlane; interior segments: plain float4 store (lane 0);
// run-spanning segments: 3 scalar atomicAdds (lane 0). ~150k atomics total.
__global__ __launch_bounds__(256) void kA0(const float4* __restrict__ sp4a,
                                           float4* __restrict__ vsum4) {
    int wave = blockIdx.x * 4 + (threadIdx.x >> 6);
    int j = threadIdx.x & 63;
    int base = wave * RUN;

    int idx = -1;
    if (j < RUN) idx = base + j;
    else if (j == 16) idx = (base + RUN < NPTS) ? base + RUN : -1;
    else if (j == 17) idx = base - 1;          // -1 when base == 0
    float4 A = make_float4(0.f, 0.f, 0.f, 0.f);
    int vx = -1;
    if (idx >= 0) {
        A = sp4a[idx];
        int cx, cy;
        vx = voxel_cell(A.x, A.y, cx, cy);
    }

    const int first = rli(vx, 0), last = rli(vx, RUN - 1);
    const bool firstExt = (rli(vx, 17) == first);
    const bool lastExt  = (rli(vx, 16) == last);

    int vprev = first;
    float sx = 0.f, sy = 0.f, sz = 0.f;
    for (int p = 0; p < RUN; p++) {
        int vp = rli(vx, p);
        if (vp != vprev) {
            if (j == 0) {
                bool ua = (vprev == first && firstExt) || (vprev == last && lastExt);
                if (ua) {
                    float* s = (float*)&vsum4[vprev];
                    unsafeAtomicAdd(s + 0, sx);
                    unsafeAtomicAdd(s + 1, sy);
                    unsafeAtomicAdd(s + 2, sz);
                } else {
                    vsum4[vprev] = make_float4(sx, sy, sz, 0.f);
                }
            }
            vprev = vp; sx = sy = sz = 0.f;
        }
        sx += rlf(A.x, p); sy += rlf(A.y, p); sz += rlf(A.z, p);
    }
    if (j == 0) {
        bool ua = (vprev == first && firstExt) || (vprev == last && lastExt);
        if (ua) {
            float* s = (float*)&vsum4[vprev];
            unsafeAtomicAdd(s + 0, sx);
            unsafeAtomicAdd(s + 1, sy);
            unsafeAtomicAdd(s + 2, sz);
        } else {
            vsum4[vprev] = make_float4(sx, sy, sz, 0.f);
        }
    }
}

// k_div: vsum -> vmean in place (cnt==0 -> zeros; poison*0 is a denormal, no NaN)
__global__ __launch_bounds__(256) void k_div(const int* __restrict__ cnt,
                                             float4* __restrict__ vsum4) {
    int v = blockIdx.x * 256 + threadIdx.x;
    if (v >= CANVASc) return;
    int c = cnt[v];
    float inv = (c > 0) ? 1.0f / (float)c : 0.f;
    float4 s = vsum4[v];
    vsum4[v] = make_float4(s.x * inv, s.y * inv, s.z * inv, 0.f);
}

// kW: pre-convert W2 (128x64) into lane-ordered bf16 hi/lo B-fragments.
__global__ __launch_bounds__(256) void kW(const float* __restrict__ W2,
                                          v8s* __restrict__ wfrag) {
    int tid = blockIdx.x * 256 + threadIdx.x;   // 1024 total
    if (tid >= 1024) return;
    int f = tid >> 6, lane = tid & 63;
    int t = f >> 2, c = f & 3;
    int q = lane >> 4, n = lane & 15;
    float v[8];
    #pragma unroll
    for (int i = 0; i < 8; i++) v[i] = W2[(c * 32 + q * 8 + i) * 64 + t * 16 + n];
    v8s h, l;
    split8(v, h, l);
    wfrag[(f * 2 + 0) * 64 + lane] = h;
    wfrag[(f * 2 + 1) * 64 + lane] = l;
}

// Per-lane feature prep. Lanes 0..15: point base+j (full record + vmean gather).
// Lane 16: voxel of pt[base+RUN]; lane 17: voxel of pt[base-1] (edge detection).
struct PtRegs {
    float4 A;
    float  e1, fcx, fcy, fcz;
    float  mx, my, mz;
    int    vx;
};
__device__ __forceinline__ PtRegs load_pt(const float4* __restrict__ sp4a,
                                          const float* __restrict__ sp1,
                                          const float4* __restrict__ vmean4,
                                          int base, int j) {
    PtRegs r;
    r.A = make_float4(0.f, 0.f, 0.f, 0.f);
    r.e1 = r.fcx = r.fcy = r.fcz = r.mx = r.my = r.mz = 0.f;
    r.vx = -1;
    int idx = -1;
    if (j < RUN) idx = base + j;
    else if (j == 16) idx = (base + RUN < NPTS) ? base + RUN : -1;
    else if (j == 17) idx = base - 1;
    if (idx >= 0) {
        float4 A = sp4a[idx];
        int cx, cy;
        int vv = voxel_cell(A.x, A.y, cx, cy);
        r.vx = vv;
        if (j < RUN) {
            r.A = A;
            r.e1 = sp1[idx];
            r.fcx = A.x - (cx * VOX_X + OFF_X);
            r.fcy = A.y - (cy * VOX_Y + OFF_Y);
            r.fcz = A.z - OFF_Z;
            float4 m = vmean4[vv];
            r.mx = m.x; r.my = m.y; r.mz = m.z;
        }
    }
    return r;
}

// kA: v1 = segment_max(relu(feat @ W1)). Edge-detected flushes: atomicMax only
// for segments that actually span a run boundary.
__global__ __launch_bounds__(256) void kA(const float4* __restrict__ sp4a,
                                          const float* __restrict__ sp1,
                                          const float4* __restrict__ vmean4,
                                          const float* __restrict__ W1,
                                          float* __restrict__ v1) {
    int wave = blockIdx.x * 4 + (threadIdx.x >> 6);
    int j = threadIdx.x & 63;
    int base = wave * RUN;

    PtRegs P = load_pt(sp4a, sp1, vmean4, base, j);

    float w[11];
    #pragma unroll
    for (int ii = 0; ii < 11; ii++) w[ii] = W1[ii * 64 + j];
    const float wx = w[0] + w[5], wy = w[1] + w[6], wz = w[2] + w[7];

    const int first = rli(P.vx, 0), last = rli(P.vx, RUN - 1);
    const bool firstExt = (rli(P.vx, 17) == first);
    const bool lastExt  = (rli(P.vx, 16) == last);

    int vprev = first;
    float rmax = 0.f;
    for (int p = 0; p < RUN; p++) {
        int vp = rli(P.vx, p);
        if (vp != vprev) {
            size_t o = (size_t)vprev * 64 + j;
            bool ua = (vprev == first && firstExt) || (vprev == last && lastExt);
            if (ua) atomicMax((int*)v1 + o, __float_as_int(rmax));
            else v1[o] = rmax;
            vprev = vp; rmax = 0.f;
        }
        float x = rlf(P.A.x, p), y = rlf(P.A.y, p), z = rlf(P.A.z, p), e0 = rlf(P.A.w, p);
        float e1 = rlf(P.e1, p), fcx = rlf(P.fcx, p), fcy = rlf(P.fcy, p), fcz = rlf(P.fcz, p);
        float mx = rlf(P.mx, p), my = rlf(P.my, p), mz = rlf(P.mz, p);
        float pf = x * wx + y * wy + z * wz + e0 * w[3] + e1 * w[4]
                 + fcx * w[8] + fcy * w[9] + fcz * w[10]
                 - (mx * w[5] + my * w[6] + mz * w[7]);
        rmax = fmaxf(rmax, pf);
    }
    {
        size_t o = (size_t)vprev * 64 + j;
        bool ua = (vprev == first && firstExt) || (vprev == last && lastExt);
        if (ua) atomicMax((int*)v1 + o, __float_as_int(rmax));
        else v1[o] = rmax;
    }
}

// kB: D[p][j] = feat2[p] @ W2 col j via MFMA 16x16x32 bf16 (hi/lo 3-product),
// feat2 row p = [pf1[p] (K 0..63), v1[vox(p)] (K 64..127)] -> segment max.
#define PSTR 68   // LDS row stride (floats): kills all bank conflicts
__global__ __launch_bounds__(256) void kB(const float4* __restrict__ sp4a,
                                          const float* __restrict__ sp1,
                                          const float4* __restrict__ vmean4,
                                          const float* __restrict__ W1,
                                          const v8s* __restrict__ wfrag,
                                          const float* __restrict__ v1,
                                          float* __restrict__ out) {
    __shared__ float s_pf[4][RUN][PSTR];   // 17408 B; pf1 staging, then D staging
    int wslot = threadIdx.x >> 6;
    int wave = blockIdx.x * 4 + wslot;
    int j = threadIdx.x & 63;
    int base = wave * RUN;

    PtRegs P = load_pt(sp4a, sp1, vmean4, base, j);

    float w[11];
    #pragma unroll
    for (int ii = 0; ii < 11; ii++) w[ii] = W1[ii * 64 + j];
    const float wx = w[0] + w[5], wy = w[1] + w[6], wz = w[2] + w[7];

    // phase 1: pf1[p][j] -> LDS (relu'd)
    for (int p = 0; p < RUN; p++) {
        float x = rlf(P.A.x, p), y = rlf(P.A.y, p), z = rlf(P.A.z, p), e0 = rlf(P.A.w, p);
        float e1 = rlf(P.e1, p), fcx = rlf(P.fcx, p), fcy = rlf(P.fcy, p), fcz = rlf(P.fcz, p);
        float mx = rlf(P.mx, p), my = rlf(P.my, p), mz = rlf(P.mz, p);
        float pf = x * wx + y * wy + z * wz + e0 * w[3] + e1 * w[4]
                 + fcx * w[8] + fcy * w[9] + fcz * w[10]
                 - (mx * w[5] + my * w[6] + mz * w[7]);
        s_pf[wslot][p][j] = fmaxf(pf, 0.f);
    }
    __builtin_amdgcn_wave_barrier();

    const int m = j & 15, q = j >> 4;

    // A-frags: chunks 0,1 from pf1 (lane-distinct LDS reads, conflict-free)
    v8s ah[4], al[4];
    #pragma unroll
    for (int c = 0; c < 2; c++) {
        float4 u0 = *(const float4*)&s_pf[wslot][m][c * 32 + q * 8];
        float4 u1 = *(const float4*)&s_pf[wslot][m][c * 32 + q * 8 + 4];
        float f[8] = {u0.x, u0.y, u0.z, u0.w, u1.x, u1.y, u1.z, u1.w};
        split8(f, ah[c], al[c]);
    }
    // chunks 2,3 from v1[vox(point m)] (constant within a segment, rides in acc)
    int vx_m = __builtin_amdgcn_ds_bpermute(m << 2, P.vx);
    {
        const float* vr = v1 + (size_t)vx_m * 64 + q * 8;
        #pragma unroll
        for (int c = 2; c < 4; c++) {
            float4 g0 = *(const float4*)(vr + (c - 2) * 32);
            float4 g1 = *(const float4*)(vr + (c - 2) * 32 + 4);
            float f[8] = {g0.x, g0.y, g0.z, g0.w, g1.x, g1.y, g1.z, g1.w};
            split8(f, ah[c], al[c]);
        }
    }
    __builtin_amdgcn_wave_barrier();   // all A reads done before D overwrites s_pf

    #pragma unroll
    for (int t = 0; t < 4; t++) {
        v8s bh[4], bl[4];
        #pragma unroll
        for (int c = 0; c < 4; c++) {
            bh[c] = wfrag[((t * 4 + c) * 2 + 0) * 64 + j];
            bl[c] = wfrag[((t * 4 + c) * 2 + 1) * 64 + j];
        }
        v4f acc = {0.f, 0.f, 0.f, 0.f};
        #pragma unroll
        for (int c = 0; c < 4; c++) {
            acc = __builtin_amdgcn_mfma_f32_16x16x32_bf16(ah[c], bh[c], acc, 0, 0, 0);
            acc = __builtin_amdgcn_mfma_f32_16x16x32_bf16(al[c], bh[c], acc, 0, 0, 0);
            acc = __builtin_amdgcn_mfma_f32_16x16x32_bf16(ah[c], bl[c], acc, 0, 0, 0);
        }
        #pragma unroll
        for (int r = 0; r < 4; r++) s_pf[wslot][q * 4 + r][t * 16 + m] = acc[r];
    }
    __builtin_amdgcn_wave_barrier();

    // epilogue: segment flush, edge-detected atomics
    const int first = rli(P.vx, 0), last = rli(P.vx, RUN - 1);
    const bool firstExt = (rli(P.vx, 17) == first);
    const bool lastExt  = (rli(P.vx, 16) == last);
    int vprev = first;
    float smax = -3.4e38f;
    for (int p = 0; p < RUN; p++) {
        int vp = rli(P.vx, p);
        if (vp != vprev) {
            float r = fmaxf(smax, 0.f);
            size_t o = (size_t)vprev * 64 + j;
            bool ua = (vprev == first && firstExt) || (vprev == last && lastExt);
            if (ua) atomicMax((int*)out + o, __float_as_int(r));
            else out[o] = r;
            vprev = vp; smax = -3.4e38f;
        }
        smax = fmaxf(smax, s_pf[wslot][p][j]);
    }
    {
        float r = fmaxf(smax, 0.f);
        size_t o = (size_t)vprev * 64 + j;
        bool ua = (vprev == first && firstExt) || (vprev == last && lastExt);
        if (ua) atomicMax((int*)out + o, __float_as_int(r));
        else out[o] = r;
    }
}

extern "C" void kernel_launch(void* const* d_in, const int* in_sizes, int n_in,
                              void* d_out, int out_size, void* d_ws, size_t ws_size,
                              hipStream_t stream) {
    const float* pts = (const float*)d_in[0];
    const float* W1  = (const float*)d_in[1];
    const float* W2  = (const float*)d_in[2];
    float* out = (float*)d_out;

    float4* sp4a  = (float4*)d_ws;                   // NPTS
    float4* vsum4 = sp4a + NPTS;                     // CANVAS
    int*    cnt   = (int*)(vsum4 + CANVASc);         // CANVAS
    int*    cursor= cnt + CANVASc;                   // CANVAS
    float*  sp1   = (float*)(cursor + CANVASc);      // NPTS
    float*  v1    = sp1 + NPTS;                      // CANVAS*64 (16B-aligned)
    v8s*    wfrag = (v8s*)(v1 + (size_t)CANVASc * 64); // 2048 v8s = 32 KB
    int*    gcur  = (int*)(wfrag + 2048);            // 1

    hipMemsetAsync(vsum4, 0, (size_t)CANVASc * 16 + (size_t)CANVASc * 4, stream); // vsum4+cnt
    hipMemsetAsync(gcur, 0, sizeof(int), stream);
    hipMemsetAsync(d_out, 0, (size_t)out_size * sizeof(float), stream);           // empty rows

    int gpts = (NPTS + 255) / 256;
    int gvox = (CANVASc + 255) / 256;
    k_stats  <<<gpts, 256, 0, stream>>>(pts, cnt);
    k_alloc  <<<gvox, 256, 0, stream>>>(cnt, cursor, gcur);
    k_scatter<<<gpts, 256, 0, stream>>>(pts, cursor, sp4a, sp1);
    kA0      <<<NRUNS / 4, 256, 0, stream>>>(sp4a, vsum4);
    k_div    <<<gvox, 256, 0, stream>>>(cnt, vsum4);
    kW       <<<4, 256, 0, stream>>>(W2, wfrag);
    kA       <<<NRUNS / 4, 256, 0, stream>>>(sp4a, sp1, vsum4, W1, v1);
    kB       <<<NRUNS / 4, 256, 0, stream>>>(sp4a, sp1, vsum4, W1, wfrag, v1, out);
}

// Round 10
// 269.749 us; speedup vs baseline: 1.5968x; 1.0101x over previous
//
#include <hip/hip_runtime.h>

#define NXc 468
#define NYc 468
#define CANVASc (468 * 468)   // 219024
#define NPTS 400000
#define RUN 16
#define NRUNS (NPTS / RUN)    // 25000 exactly

#define PCMIN_X (-74.88f)
#define PCMIN_Y (-74.88f)
#define VOX_X 0.32f
#define VOX_Y 0.32f
#define OFF_X (-74.72f)
#define OFF_Y (-74.72f)
#define OFF_Z (1.0f)

typedef __attribute__((ext_vector_type(8))) short v8s;   // 8 bf16 (4 VGPRs)
typedef __attribute__((ext_vector_type(4))) float v4f;   // MFMA acc

__device__ __forceinline__ float rlf(float x, int p) {
    return __int_as_float(__builtin_amdgcn_readlane(__float_as_int(x), p));
}
__device__ __forceinline__ int rli(int x, int p) {
    return __builtin_amdgcn_readlane(x, p);
}
__device__ __forceinline__ unsigned bfh(float x) {    // bf16 RNE hi bits
    unsigned u = __float_as_uint(x);
    unsigned r = u + 0x7FFFu + ((u >> 16) & 1u);
    return r & 0xFFFF0000u;
}
__device__ __forceinline__ void split8(const float* f, v8s& h, v8s& l) {
    #pragma unroll
    for (int i = 0; i < 8; i++) {
        unsigned hb = bfh(f[i]);
        h[i] = (short)(hb >> 16);
        float lo = f[i] - __uint_as_float(hb);
        l[i] = (short)(bfh(lo) >> 16);
    }
}

__device__ __forceinline__ int voxel_cell(float x, float y, int& cx, int& cy) {
    cx = (int)floorf((x - PCMIN_X) / VOX_X);
    cy = (int)floorf((y - PCMIN_Y) / VOX_Y);
    cx = min(max(cx, 0), NXc - 1);
    cy = min(max(cy, 0), NYc - 1);
    return cy * NXc + cx;
}

// Pass 0: per-voxel counts + per-point voxel key (coalesced)
__global__ __launch_bounds__(256) void k_stats(const float* __restrict__ pts,
                                               int* __restrict__ cnt,
                                               int* __restrict__ key) {
    int i = blockIdx.x * 256 + threadIdx.x;
    if (i >= NPTS) return;
    float x = pts[i * 5 + 0], y = pts[i * 5 + 1];
    int cx, cy;
    int fl = voxel_cell(x, y, cx, cy);
    key[i] = fl;
    atomicAdd(&cnt[fl], 1);
}

// Pass 1: exclusive-scan alloc -> cursor
__global__ __launch_bounds__(256) void k_alloc(const int* __restrict__ cnt,
                                               int* __restrict__ cursor,
                                               int* __restrict__ gcur) {
    int v = blockIdx.x * 256 + threadIdx.x;
    int lane = threadIdx.x & 63;
    int c = (v < CANVASc) ? cnt[v] : 0;
    int scan = c;
    #pragma unroll
    for (int off = 1; off < 64; off <<= 1) {
        int t = __shfl_up(scan, off, 64);
        if (lane >= off) scan += t;
    }
    int total = __shfl(scan, 63, 64);
    int base = 0;
    if (lane == 0 && total > 0) base = atomicAdd(gcur, total);
    base = __shfl(base, 0, 64);
    if (v < CANVASc) cursor[v] = base + scan - c;
}

// Pass 2: index-only scatter (4B random writes instead of 20B records)
__global__ __launch_bounds__(256) void k_scatter(const int* __restrict__ key,
                                                 int* __restrict__ cursor,
                                                 int* __restrict__ ord) {
    int i = blockIdx.x * 256 + threadIdx.x;
    if (i >= NPTS) return;
    int fl = key[i];
    int pos = atomicAdd(&cursor[fl], 1);
    ord[pos] = i;
}

// gather one point record (random 20B, pts is L2/L3-warm)
__device__ __forceinline__ void gather_pt(const float* __restrict__ pts, int pi,
                                          float4& A, float& e1) {
    const float* pp = pts + (size_t)pi * 5;
    __builtin_memcpy(&A, pp, 16);   // 4B-aligned dwordx4
    e1 = pp[4];
}

// kA0: per-voxel xyz sums from sorted order (gather via ord).
__global__ __launch_bounds__(256) void kA0(const int* __restrict__ ord,
                                           const float* __restrict__ pts,
                                           float4* __restrict__ vsum4) {
    int wave = blockIdx.x * 4 + (threadIdx.x >> 6);
    int j = threadIdx.x & 63;
    int base = wave * RUN;

    int idx = -1;
    if (j < RUN) idx = base + j;
    else if (j == 16) idx = (base + RUN < NPTS) ? base + RUN : -1;
    else if (j == 17) idx = base - 1;
    float4 A = make_float4(0.f, 0.f, 0.f, 0.f);
    int vx = -1;
    if (idx >= 0) {
        int pi = ord[idx];
        float e1d;
        gather_pt(pts, pi, A, e1d);
        int cx, cy;
        vx = voxel_cell(A.x, A.y, cx, cy);
    }

    const int first = rli(vx, 0), last = rli(vx, RUN - 1);
    const bool firstExt = (rli(vx, 17) == first);
    const bool lastExt  = (rli(vx, 16) == last);

    int vprev = first;
    float sx = 0.f, sy = 0.f, sz = 0.f;
    for (int p = 0; p < RUN; p++) {
        int vp = rli(vx, p);
        if (vp != vprev) {
            if (j == 0) {
                bool ua = (vprev == first && firstExt) || (vprev == last && lastExt);
                if (ua) {
                    float* s = (float*)&vsum4[vprev];
                    unsafeAtomicAdd(s + 0, sx);
                    unsafeAtomicAdd(s + 1, sy);
                    unsafeAtomicAdd(s + 2, sz);
                } else {
                    vsum4[vprev] = make_float4(sx, sy, sz, 0.f);
                }
            }
            vprev = vp; sx = sy = sz = 0.f;
        }
        sx += rlf(A.x, p); sy += rlf(A.y, p); sz += rlf(A.z, p);
    }
    if (j == 0) {
        bool ua = (vprev == first && firstExt) || (vprev == last && lastExt);
        if (ua) {
            float* s = (float*)&vsum4[vprev];
            unsafeAtomicAdd(s + 0, sx);
            unsafeAtomicAdd(s + 1, sy);
            unsafeAtomicAdd(s + 2, sz);
        } else {
            vsum4[vprev] = make_float4(sx, sy, sz, 0.f);
        }
    }
}

// k_div: vsum -> vmean in place
__global__ __launch_bounds__(256) void k_div(const int* __restrict__ cnt,
                                             float4* __restrict__ vsum4) {
    int v = blockIdx.x * 256 + threadIdx.x;
    if (v >= CANVASc) return;
    int c = cnt[v];
    float inv = (c > 0) ? 1.0f / (float)c : 0.f;
    float4 s = vsum4[v];
    vsum4[v] = make_float4(s.x * inv, s.y * inv, s.z * inv, 0.f);
}

// kW: bf16 hi/lo B-fragments for W2 (4 tiles x 4 K-chunks) and W1 (4 tiles,
// K=32 single chunk, rows >= 11 zero). B[k][n]: n=lane&15, k=c*32+(lane>>4)*8+i.
__global__ __launch_bounds__(256) void kW(const float* __restrict__ W1,
                                          const float* __restrict__ W2,
                                          v8s* __restrict__ w1frag,
                                          v8s* __restrict__ w2frag) {
    int tid = blockIdx.x * 256 + threadIdx.x;   // 1280 total
    if (tid < 1024) {
        int f = tid >> 6, lane = tid & 63;
        int t = f >> 2, c = f & 3;
        int q = lane >> 4, n = lane & 15;
        float v[8];
        #pragma unroll
        for (int i = 0; i < 8; i++) v[i] = W2[(c * 32 + q * 8 + i) * 64 + t * 16 + n];
        v8s h, l;
        split8(v, h, l);
        w2frag[(f * 2 + 0) * 64 + lane] = h;
        w2frag[(f * 2 + 1) * 64 + lane] = l;
    } else if (tid < 1280) {
        int f = (tid - 1024) >> 6, lane = (tid - 1024) & 63;
        int q = lane >> 4, n = lane & 15;
        float v[8];
        #pragma unroll
        for (int i = 0; i < 8; i++) {
            int k = q * 8 + i;
            v[i] = (k < 11) ? W1[k * 64 + f * 16 + n] : 0.f;
        }
        v8s h, l;
        split8(v, h, l);
        w1frag[(f * 2 + 0) * 64 + lane] = h;
        w1frag[(f * 2 + 1) * 64 + lane] = l;
    }
}

// Per-lane prep: lanes 0..15 gather point base+j + vmean; lanes 16/17 peek
// neighbor voxels for run-edge detection.
struct PtRegs {
    float4 A;
    float  e1, fcx, fcy, fcz;
    float  mx, my, mz;
    int    vx;
};
__device__ __forceinline__ PtRegs load_pt(const int* __restrict__ ord,
                                          const float* __restrict__ pts,
                                          const float4* __restrict__ vmean4,
                                          int base, int j) {
    PtRegs r;
    r.A = make_float4(0.f, 0.f, 0.f, 0.f);
    r.e1 = r.fcx = r.fcy = r.fcz = r.mx = r.my = r.mz = 0.f;
    r.vx = -1;
    int idx = -1;
    if (j < RUN) idx = base + j;
    else if (j == 16) idx = (base + RUN < NPTS) ? base + RUN : -1;
    else if (j == 17) idx = base - 1;
    if (idx >= 0) {
        int pi = ord[idx];
        float4 A; float e1;
        gather_pt(pts, pi, A, e1);
        int cx, cy;
        int vv = voxel_cell(A.x, A.y, cx, cy);
        r.vx = vv;
        if (j < RUN) {
            r.A = A;
            r.e1 = e1;
            r.fcx = A.x - (cx * VOX_X + OFF_X);
            r.fcy = A.y - (cy * VOX_Y + OFF_Y);
            r.fcz = A.z - OFF_Z;
            float4 m = vmean4[vv];
            r.mx = m.x; r.my = m.y; r.mz = m.z;
        }
    }
    return r;
}

#define PSTR 68   // LDS row stride (floats)

// Shared phase-1: features -> LDS rows -> MFMA (K=32, 12 mfma) -> relu(D) -> LDS.
// On return s_pf rows 0..15 hold relu'd pf1[p][0..63].
__device__ __forceinline__ void phase1_mfma(float (*s_pf)[PSTR], const PtRegs& P,
                                            const v8s* __restrict__ w1frag, int j) {
    if (j < RUN) {
        float* row = s_pf[j];
        row[0] = P.A.x; row[1] = P.A.y; row[2] = P.A.z; row[3] = P.A.w; row[4] = P.e1;
        row[5] = P.A.x - P.mx; row[6] = P.A.y - P.my; row[7] = P.A.z - P.mz;
        row[8] = P.fcx; row[9] = P.fcy; row[10] = P.fcz;
        #pragma unroll
        for (int t = 11; t < 16; t++) row[t] = 0.f;
    }
    __builtin_amdgcn_wave_barrier();

    const int m = j & 15, q = j >> 4;
    v8s fh = {0,0,0,0,0,0,0,0}, fl_ = {0,0,0,0,0,0,0,0};
    if (q < 2) {
        float f8[8];
        #pragma unroll
        for (int i = 0; i < 8; i++) f8[i] = s_pf[m][q * 8 + i];
        split8(f8, fh, fl_);
    }
    v4f d[4];
    #pragma unroll
    for (int t = 0; t < 4; t++) {
        v8s bh = w1frag[(t * 2 + 0) * 64 + j];
        v8s bl = w1frag[(t * 2 + 1) * 64 + j];
        v4f acc = {0.f, 0.f, 0.f, 0.f};
        acc = __builtin_amdgcn_mfma_f32_16x16x32_bf16(fh,  bh, acc, 0, 0, 0);
        acc = __builtin_amdgcn_mfma_f32_16x16x32_bf16(fl_, bh, acc, 0, 0, 0);
        acc = __builtin_amdgcn_mfma_f32_16x16x32_bf16(fh,  bl, acc, 0, 0, 0);
        d[t] = acc;
    }
    __builtin_amdgcn_wave_barrier();   // feature reads complete before overwrite
    #pragma unroll
    for (int t = 0; t < 4; t++)
        #pragma unroll
        for (int r = 0; r < 4; r++)
            s_pf[q * 4 + r][t * 16 + m] = fmaxf(d[t][r], 0.f);
    __builtin_amdgcn_wave_barrier();
}

// kA: v1 = segment_max(pf1) with edge-detected atomics.
__global__ __launch_bounds__(256) void kA(const int* __restrict__ ord,
                                          const float* __restrict__ pts,
                                          const float4* __restrict__ vmean4,
                                          const v8s* __restrict__ w1frag,
                                          float* __restrict__ v1) {
    __shared__ float s_pf[4][RUN][PSTR];
    int wslot = threadIdx.x >> 6;
    int wave = blockIdx.x * 4 + wslot;
    int j = threadIdx.x & 63;
    int base = wave * RUN;

    PtRegs P = load_pt(ord, pts, vmean4, base, j);
    phase1_mfma(s_pf[wslot], P, w1frag, j);

    const int first = rli(P.vx, 0), last = rli(P.vx, RUN - 1);
    const bool firstExt = (rli(P.vx, 17) == first);
    const bool lastExt  = (rli(P.vx, 16) == last);
    int vprev = first;
    float smax = 0.f;
    for (int p = 0; p < RUN; p++) {
        int vp = rli(P.vx, p);
        if (vp != vprev) {
            size_t o = (size_t)vprev * 64 + j;
            bool ua = (vprev == first && firstExt) || (vprev == last && lastExt);
            if (ua) atomicMax((int*)v1 + o, __float_as_int(smax));
            else v1[o] = smax;
            vprev = vp; smax = 0.f;
        }
        smax = fmaxf(smax, s_pf[wslot][p][j]);
    }
    {
        size_t o = (size_t)vprev * 64 + j;
        bool ua = (vprev == first && firstExt) || (vprev == last && lastExt);
        if (ua) atomicMax((int*)v1 + o, __float_as_int(smax));
        else v1[o] = smax;
    }
}

// kB: D[p][j] = [pf1[p], v1[vox(p)]] @ W2 via MFMA -> segment max -> out.
__global__ __launch_bounds__(256) void kB(const int* __restrict__ ord,
                                          const float* __restrict__ pts,
                                          const float4* __restrict__ vmean4,
                                          const v8s* __restrict__ w1frag,
                                          const v8s* __restrict__ w2frag,
                                          const float* __restrict__ v1,
                                          float* __restrict__ out) {
    __shared__ float s_pf[4][RUN][PSTR];
    int wslot = threadIdx.x >> 6;
    int wave = blockIdx.x * 4 + wslot;
    int j = threadIdx.x & 63;
    int base = wave * RUN;

    PtRegs P = load_pt(ord, pts, vmean4, base, j);
    phase1_mfma(s_pf[wslot], P, w1frag, j);

    const int m = j & 15, q = j >> 4;

    // A-frags: chunks 0,1 = pf1 rows (lane-distinct LDS reads)
    v8s ah[4], al[4];
    #pragma unroll
    for (int c = 0; c < 2; c++) {
        float f[8];
        #pragma unroll
        for (int i = 0; i < 8; i++) f[i] = s_pf[wslot][m][c * 32 + q * 8 + i];
        split8(f, ah[c], al[c]);
    }
    // chunks 2,3 = v1[vox(point m)] (segment-constant: rides inside the acc)
    int vx_m = __builtin_amdgcn_ds_bpermute(m << 2, P.vx);
    {
        const float* vr = v1 + (size_t)vx_m * 64 + q * 8;
        #pragma unroll
        for (int c = 2; c < 4; c++) {
            float f[8];
            #pragma unroll
            for (int i = 0; i < 8; i++) f[i] = vr[(c - 2) * 32 + i];
            split8(f, ah[c], al[c]);
        }
    }
    __builtin_amdgcn_wave_barrier();   // A reads done before D overwrites s_pf

    #pragma unroll
    for (int t = 0; t < 4; t++) {
        v8s bh[4], bl[4];
        #pragma unroll
        for (int c = 0; c < 4; c++) {
            bh[c] = w2frag[((t * 4 + c) * 2 + 0) * 64 + j];
            bl[c] = w2frag[((t * 4 + c) * 2 + 1) * 64 + j];
        }
        v4f acc = {0.f, 0.f, 0.f, 0.f};
        #pragma unroll
        for (int c = 0; c < 4; c++) {
            acc = __builtin_amdgcn_mfma_f32_16x16x32_bf16(ah[c], bh[c], acc, 0, 0, 0);
            acc = __builtin_amdgcn_mfma_f32_16x16x32_bf16(al[c], bh[c], acc, 0, 0, 0);
            acc = __builtin_amdgcn_mfma_f32_16x16x32_bf16(ah[c], bl[c], acc, 0, 0, 0);
        }
        #pragma unroll
        for (int r = 0; r < 4; r++) s_pf[wslot][q * 4 + r][t * 16 + m] = acc[r];
    }
    __builtin_amdgcn_wave_barrier();

    const int first = rli(P.vx, 0), last = rli(P.vx, RUN - 1);
    const bool firstExt = (rli(P.vx, 17) == first);
    const bool lastExt  = (rli(P.vx, 16) == last);
    int vprev = first;
    float smax = -3.4e38f;
    for (int p = 0; p < RUN; p++) {
        int vp = rli(P.vx, p);
        if (vp != vprev) {
            float r = fmaxf(smax, 0.f);
            size_t o = (size_t)vprev * 64 + j;
            bool ua = (vprev == first && firstExt) || (vprev == last && lastExt);
            if (ua) atomicMax((int*)out + o, __float_as_int(r));
            else out[o] = r;
            vprev = vp; smax = -3.4e38f;
        }
        smax = fmaxf(smax, s_pf[wslot][p][j]);
    }
    {
        float r = fmaxf(smax, 0.f);
        size_t o = (size_t)vprev * 64 + j;
        bool ua = (vprev == first && firstExt) || (vprev == last && lastExt);
        if (ua) atomicMax((int*)out + o, __float_as_int(r));
        else out[o] = r;
    }
}

extern "C" void kernel_launch(void* const* d_in, const int* in_sizes, int n_in,
                              void* d_out, int out_size, void* d_ws, size_t ws_size,
                              hipStream_t stream) {
    const float* pts = (const float*)d_in[0];
    const float* W1  = (const float*)d_in[1];
    const float* W2  = (const float*)d_in[2];
    float* out = (float*)d_out;

    float4* vsum4  = (float4*)d_ws;                         // CANVAS float4
    float*  v1     = (float*)(vsum4 + CANVASc);             // CANVAS*64 (16B aligned)
    v8s*    w2frag = (v8s*)(v1 + (size_t)CANVASc * 64);     // 2048 v8s
    v8s*    w1frag = w2frag + 2048;                         // 512 v8s
    int*    ord    = (int*)(w1frag + 512);                  // NPTS
    int*    key    = ord + NPTS;                            // NPTS
    int*    cnt    = key + NPTS;                            // CANVAS
    int*    gcur   = cnt + CANVASc;                         // 1
    int*    cursor = gcur + 1;                              // CANVAS

    hipMemsetAsync(vsum4, 0, (size_t)CANVASc * 16, stream);
    hipMemsetAsync(cnt, 0, (size_t)(CANVASc + 1) * 4, stream);      // cnt + gcur
    hipMemsetAsync(d_out, 0, (size_t)out_size * sizeof(float), stream);

    int gpts = (NPTS + 255) / 256;
    int gvox = (CANVASc + 255) / 256;
    k_stats  <<<gpts, 256, 0, stream>>>(pts, cnt, key);
    k_alloc  <<<gvox, 256, 0, stream>>>(cnt, cursor, gcur);
    k_scatter<<<gpts, 256, 0, stream>>>(key, cursor, ord);
    kW       <<<5, 256, 0, stream>>>(W1, W2, w1frag, w2frag);
    kA0      <<<NRUNS / 4, 256, 0, stream>>>(ord, pts, vsum4);
    k_div    <<<gvox, 256, 0, stream>>>(cnt, vsum4);
    kA       <<<NRUNS / 4, 256, 0, stream>>>(ord, pts, vsum4, w1frag, v1);
    kB       <<<NRUNS / 4, 256, 0, stream>>>(ord, pts, vsum4, w1frag, w2frag, v1, out);
}